// Round 9
// baseline (174.772 us; speedup 1.0000x reference)
//
#include <hip/hip_runtime.h>
#include <hip/hip_bf16.h>
#include <stdint.h>

typedef __bf16 bf16_t;
typedef __bf16 bf16x4_t __attribute__((ext_vector_type(4)));
typedef __bf16 bf16x8_t __attribute__((ext_vector_type(8)));
typedef float f32x4_t __attribute__((ext_vector_type(4)));

#define S_LEN   2048
#define DMODEL  1024
#define NH      16
#define DH      64
// masks applied BEFORE scaling: masked logit = -1e9/8; work in log2 domain.
#define LOG2E   1.4426950408889634f
#define SCL     (0.125f * LOG2E)            // st * SCL == (st/8)*log2(e)
#define EPS2    (-1.8033688e8f)             // (-1e9/8) * log2(e)

#define MFMA(a, b, c) __builtin_amdgcn_mfma_f32_16x16x32_bf16(a, b, c, 0, 0, 0)

#define GLOAD_LDS16(gsrc, ldst)                                         \
  __builtin_amdgcn_global_load_lds(                                     \
      (__attribute__((address_space(1))) void*)(void*)(gsrc),           \
      (__attribute__((address_space(3))) void*)(void*)(ldst), 16, 0, 0)

// ---------------- fp32 -> bf16 convert (x) ----------------
__global__ void k_cvt_bf16(const float* __restrict__ in, bf16_t* __restrict__ out, int n4) {
  int i = blockIdx.x * blockDim.x + threadIdx.x;
  if (i >= n4) return;
  float4 v = reinterpret_cast<const float4*>(in)[i];
  bf16x4_t o = {(bf16_t)v.x, (bf16_t)v.y, (bf16_t)v.z, (bf16_t)v.w};
  reinterpret_cast<bf16x4_t*>(out)[i] = o;
}

// ---------------- pad mask -> additive log2-domain float ----------------
__global__ void k_mask(const int* __restrict__ am, float* __restrict__ mskf, int n) {
  int i = blockIdx.x * blockDim.x + threadIdx.x;
  if (i < n) mskf[i] = am[i] ? 0.f : EPS2;
}

// ---------------- fp32 [R][C] -> bf16 [C][R] (weight transpose) ----------------
__global__ void k_transpose_bf16(const float* __restrict__ in, bf16_t* __restrict__ out,
                                 int R, int C) {
  __shared__ float tile[32][33];
  int c0 = blockIdx.x * 32, r0 = blockIdx.y * 32;
  int tx = threadIdx.x, ty = threadIdx.y;   // block (32,8)
  for (int i = ty; i < 32; i += 8)
    tile[i][tx] = in[(size_t)(r0 + i) * C + (c0 + tx)];
  __syncthreads();
  for (int i = ty; i < 32; i += 8)
    out[(size_t)(c0 + i) * R + (r0 + tx)] = (bf16_t)tile[tx][i];
}

// ---------------- bf16 GEMM: C[M][N] = A[M][K] * Bt[N][K]^T + bias ----------------
// BK=32, 3-buffer LDS, prefetch 2 tiles ahead with counted vmcnt: 48 KB/block
// (MODE 0) -> 3 blocks/CU, all 768 blocks co-resident, 12 waves/CU; each stage
// has ~2 compute phases to cover HBM latency. Both-sides XOR-(row&3) swizzle
// on 16B columns (64 B rows) -> 2-way bank aliasing (free). T1 XCD swizzle.
// MODE 0: 128x128 tile, QKV epilogue; MODE 1: 128x64 tile, fp32 Out epilogue.
template<int MODE>
__global__ __launch_bounds__(256)
void k_gemm(const bf16_t* __restrict__ A, const bf16_t* __restrict__ Bt,
            const float* __restrict__ bias,
            bf16_t* __restrict__ Qb, bf16_t* __restrict__ Kb, bf16_t* __restrict__ Vt,
            float* __restrict__ Out, int M, int N, int K) {
  constexpr int BN  = (MODE == 0) ? 128 : 64;   // block N-tile
  constexpr int JN  = BN / 32;                  // acc cols per wave (4 or 2)
  constexpr int BST = BN / 64;                  // B stage instrs per wave (2 or 1)
  __shared__ alignas(16) bf16_t As[3][128 * 32];
  __shared__ alignas(16) bf16_t Bs[3][BN * 32];
  const int tid = threadIdx.x;
  const int lane = tid & 63;
  const int w = tid >> 6;
  // T1: XCD-aware bijective swizzle (nwg % 8 == 0 for both call sites)
  const int nwg = gridDim.x * gridDim.y;
  int lin = blockIdx.y * gridDim.x + blockIdx.x;
  lin = (lin & 7) * (nwg >> 3) + (lin >> 3);
  const int m0 = (lin / gridDim.x) * 128;
  const int n0 = (lin % gridDim.x) * BN;
  const int wm = (w >> 1) * 64, wn = (w & 1) * (BN / 2);
  const int l15 = lane & 15, lg = lane >> 4;
  const int sr   = lane >> 2;                        // row within 16-row group
  const int scl  = (((lane & 3) ^ (sr & 3)) * 8);    // pre-swizzled source col (elems)
  const int swzc = l15 & 3;                          // read-side XOR on 16B-col idx

  f32x4_t acc[4][JN] = {};

#define GSTAGE(k0_, buf_)                                                        \
  do {                                                                           \
    _Pragma("unroll")                                                            \
    for (int p = 0; p < 2; ++p) {                                                \
      const int rb = p * 64 + w * 16;   /* wave-uniform 16-row group */          \
      GLOAD_LDS16(&A[(size_t)(m0 + rb + sr) * K + (k0_) + scl],                  \
                  &As[buf_][rb * 32]);                                           \
    }                                                                            \
    _Pragma("unroll")                                                            \
    for (int p = 0; p < BST; ++p) {                                              \
      const int rb = p * 64 + w * 16;                                            \
      GLOAD_LDS16(&Bt[(size_t)(n0 + rb + sr) * K + (k0_) + scl],                 \
                  &Bs[buf_][rb * 32]);                                           \
    }                                                                            \
  } while (0)

  GSTAGE(0, 0);
  GSTAGE(32, 1);
  int cur = 0, nxt = 1, fut = 2;
  for (int k0 = 0; k0 < K; k0 += 32) {
    if (k0 + 64 < K) {
      GSTAGE(k0 + 64, fut);
      if (MODE == 0) asm volatile("s_waitcnt vmcnt(8)" ::: "memory");
      else           asm volatile("s_waitcnt vmcnt(6)" ::: "memory");
    } else if (k0 + 32 < K) {
      if (MODE == 0) asm volatile("s_waitcnt vmcnt(4)" ::: "memory");
      else           asm volatile("s_waitcnt vmcnt(3)" ::: "memory");
    } else {
      asm volatile("s_waitcnt vmcnt(0)" ::: "memory");
    }
    __builtin_amdgcn_s_barrier();        // all waves' cur-tile loads landed
    __builtin_amdgcn_sched_barrier(0);
    const bf16_t* Asb = As[cur];
    const bf16_t* Bsb = Bs[cur];
    bf16x8_t a[4], b[JN];
#pragma unroll
    for (int i = 0; i < 4; ++i)
      a[i] = *reinterpret_cast<const bf16x8_t*>(
          &Asb[(wm + i * 16 + l15) * 32 + ((lg ^ swzc) * 8)]);
#pragma unroll
    for (int j = 0; j < JN; ++j)
      b[j] = *reinterpret_cast<const bf16x8_t*>(
          &Bsb[(wn + j * 16 + l15) * 32 + ((lg ^ swzc) * 8)]);
    __builtin_amdgcn_s_setprio(1);
#pragma unroll
    for (int i = 0; i < 4; ++i)
#pragma unroll
      for (int j = 0; j < JN; ++j)
        acc[i][j] = MFMA(a[i], b[j], acc[i][j]);
    __builtin_amdgcn_s_setprio(0);
    __builtin_amdgcn_sched_barrier(0);   // pin reads/MFMAs before the barrier
    __builtin_amdgcn_s_barrier();        // all waves done reading cur
    const int t = cur; cur = nxt; nxt = fut; fut = t;
  }
#undef GSTAGE

  const int rbase = lg * 4;
#pragma unroll
  for (int i = 0; i < 4; ++i)
#pragma unroll
    for (int j = 0; j < JN; ++j) {
      int ncol = n0 + wn + j * 16 + l15;
      float bs = bias[ncol];
#pragma unroll
      for (int r = 0; r < 4; ++r) {
        int m = m0 + wm + i * 16 + rbase + r;
        float v = acc[i][j][r] + bs;
        if (MODE == 1) {
          Out[(size_t)m * N + ncol] = v;
        } else {
          int b2 = m >> 11, s = m & 2047;         // S = 2048
          int t = ncol >> 10, nn = ncol & 1023;   // 0:Q 1:K 2:V
          int h = nn >> 6, d = nn & 63;
          size_t bh = (size_t)b2 * NH + h;
          if (t == 0)      Qb[(bh * S_LEN + s) * DH + d] = (bf16_t)v;
          else if (t == 1) Kb[(bh * S_LEN + s) * DH + d] = (bf16_t)v;
          else             Vt[(bh * DH + d) * S_LEN + s] = (bf16_t)v;
        }
      }
    }
}

// ---------------- per-(b,h) mean of V over all S keys (all-masked-row fallback) ------
__global__ __launch_bounds__(256)
void k_vmean(const bf16_t* __restrict__ Vt, float* __restrict__ vmean) {
  const int bh = blockIdx.x;
  const int t = threadIdx.x;
  const int d = t >> 2, q = t & 3;
  const bf16_t* vp = Vt + ((size_t)bh * DH + d) * S_LEN + q * 512;
  float s = 0.f;
  for (int i = 0; i < 512; i += 8) {
    bf16x8_t v = *reinterpret_cast<const bf16x8_t*>(&vp[i]);
    for (int j = 0; j < 8; ++j) s += (float)v[j];
  }
  __shared__ float part[256];
  part[t] = s;
  __syncthreads();
  if (q == 0)
    vmean[bh * DH + d] = (part[t] + part[t + 1] + part[t + 2] + part[t + 3]) * (1.f / 2048.f);
}

// ---------------- flash attention, split-K balanced blocks (unchanged) ----------------
__global__ __launch_bounds__(256, 2)
void k_attn(const bf16_t* __restrict__ Qb, const bf16_t* __restrict__ Kb,
            const bf16_t* __restrict__ Vt, const float* __restrict__ mskf,
            const float* __restrict__ vmean, bf16_t* __restrict__ ctxb,
            float* __restrict__ Opart, float* __restrict__ mlb) {
  __shared__ alignas(16) char smem[65536];   // K: 2 x 16KB @0; V^T: 2 x 16KB @32768
  const int tid = threadIdx.x, lane = tid & 63, w = tid >> 6;
  const int bh = blockIdx.x, b = bh >> 4, h = bh & 15;  // bh fast => K/V L2-resident
  const int j = blockIdx.y;                  // 0..15
  const int u = j >> 1, role = j & 1;
  const int sH = 15 - u, sL = u;
  const int l15 = lane & 15, lg = lane >> 4;
  const bf16_t* Qp = Qb + (size_t)bh * S_LEN * DH;
  const char*   Kg = (const char*)(Kb + (size_t)bh * S_LEN * DH);  // row = key, 128 B
  const char*   Vg = (const char*)(Vt + (size_t)bh * DH * S_LEN);  // row = d, 4096 B
  const float*  mp = mskf + b * S_LEN;

  // staging lane constants (pre-swizzled global source cols, 16B units)
  const int srow = lane >> 3;                               // K: 8 rows/iter
  const int scol = ((lane & 7) * 16) ^ (srow * 16);
  const int vrow = lane >> 4;                               // V: 4 rows/iter
  const int swz  = 16 * (l15 & 7);

#define STAGE_PH(ph_, buf_)                                                        \
  do {                                                                             \
    const int kb_ = (ph_) * 128;                                                   \
    _Pragma("unroll")                                                              \
    for (int jj = 0; jj < 4; ++jj) {                                               \
      const int rk = w * 32 + jj * 8;                                              \
      GLOAD_LDS16(Kg + (size_t)(kb_ + rk + srow) * 128 + scol,                     \
                  smem + (buf_) * 16384 + rk * 128);                               \
      const int rv = w * 16 + jj * 4;                                              \
      const int vc = ((lane & 15) * 16) ^ ((((jj << 2) + vrow) & 7) * 16);         \
      GLOAD_LDS16(Vg + (size_t)(rv + vrow) * 4096 + (size_t)kb_ * 2 + vc,          \
                  smem + 32768 + (buf_) * 16384 + rv * 256);                       \
    }                                                                              \
  } while (0)

#define QK_SUB(S_, STA, STB)                                                       \
  _Pragma("unroll")                                                                \
  for (int t = 0; t < 4; ++t) {                                                    \
    const int rbyte = ((S_) * 64 + t * 16 + l15) * 128;                            \
    bf16x8_t k0 = *reinterpret_cast<const bf16x8_t*>(Ksb + rbyte + ((16 * lg) ^ swz));       \
    bf16x8_t k1 = *reinterpret_cast<const bf16x8_t*>(Ksb + rbyte + ((64 + 16 * lg) ^ swz));  \
    f32x4_t s = {}; s = MFMA(k0, qA0, s); s = MFMA(k1, qA1, s); STA[t] = s;        \
    f32x4_t s2 = {}; s2 = MFMA(k0, qB0, s2); s2 = MFMA(k1, qB1, s2); STB[t] = s2;  \
  }

#define SM_PACK(ST, MK, M_, L_, PO, PF, QG, CAUSAL, KB0)                           \
  do {                                                                             \
    float e[16]; float pmax = -3.0e38f;                                            \
    _Pragma("unroll")                                                              \
    for (int t = 0; t < 4; ++t)                                                    \
      _Pragma("unroll")                                                            \
      for (int r = 0; r < 4; ++r) {                                                \
        float v = fmaf(ST[t][r], SCL, MK[t][r]);                                   \
        if (CAUSAL) {                                                              \
          int k = (KB0) + t * 16 + lg * 4 + r;                                     \
          v = (k <= (QG)) ? v : EPS2;                                              \
        }                                                                          \
        e[t * 4 + r] = v; pmax = fmaxf(pmax, v);                                   \
      }                                                                            \
    pmax = fmaxf(pmax, __shfl_xor(pmax, 16));                                      \
    pmax = fmaxf(pmax, __shfl_xor(pmax, 32));                                      \
    if (!__all(pmax <= (M_) + 8.f)) {                                              \
      float mn = fmaxf(M_, pmax); float sc = exp2f((M_) - mn);                     \
      M_ = mn; L_ *= sc;                                                           \
      _Pragma("unroll") for (int f = 0; f < 4; ++f) PO[f] *= sc;                   \
    }                                                                              \
    float ps = 0.f;                                                                \
    _Pragma("unroll")                                                              \
    for (int i = 0; i < 16; ++i) { e[i] = exp2f(e[i] - (M_)); ps += e[i]; }        \
    ps += __shfl_xor(ps, 16); ps += __shfl_xor(ps, 32);                            \
    L_ += ps;                                                                      \
    _Pragma("unroll")                                                              \
    for (int g = 0; g < 2; ++g) {                                                  \
      union { uint32_t u2[4]; bf16x8_t v; } pk_;                                   \
      _Pragma("unroll")                                                            \
      for (int jj = 0; jj < 4; ++jj)                                               \
        asm("v_cvt_pk_bf16_f32 %0, %1, %2"                                         \
            : "=v"(pk_.u2[jj]) : "v"(e[8 * g + 2 * jj]), "v"(e[8 * g + 2 * jj + 1])); \
      PF[g] = pk_.v;                                                               \
    }                                                                              \
  } while (0)

#define PV_SUB(S_, PFA, PFB)                                                       \
  _Pragma("unroll")                                                                \
  for (int g = 0; g < 2; ++g)                                                      \
    _Pragma("unroll")                                                              \
    for (int f = 0; f < 4; ++f) {                                                  \
      const int rbyte = (f * 16 + l15) * 256;                                      \
      const int cb = (S_) * 128 + 64 * g + 8 * lg;                                 \
      bf16x4_t va = *reinterpret_cast<const bf16x4_t*>(Vsb + rbyte + (cb ^ swz));          \
      bf16x4_t vb = *reinterpret_cast<const bf16x4_t*>(Vsb + rbyte + ((cb + 32) ^ swz));   \
      bf16x8_t vv = {va[0], va[1], va[2], va[3], vb[0], vb[1], vb[2], vb[3]};      \
      poA[f] = MFMA(vv, PFA[g], poA[f]);                                           \
      poB[f] = MFMA(vv, PFB[g], poB[f]);                                           \
    }

  // ---- one stripe segment: phases [ph0, ph1) of stripe qst_ ----
  auto run_segment = [&](int qst_, int ph0, int ph1, int mode, int slot) {
    const int qbase = qst_ * 128 + w * 32;
    const int qg0 = qbase + l15, qg1 = qbase + 16 + l15;
    const bf16x8_t qA0 = *reinterpret_cast<const bf16x8_t*>(&Qp[qg0 * DH + 8 * lg]);
    const bf16x8_t qA1 = *reinterpret_cast<const bf16x8_t*>(&Qp[qg0 * DH + 32 + 8 * lg]);
    const bf16x8_t qB0 = *reinterpret_cast<const bf16x8_t*>(&Qp[qg1 * DH + 8 * lg]);
    const bf16x8_t qB1 = *reinterpret_cast<const bf16x8_t*>(&Qp[qg1 * DH + 32 + 8 * lg]);
    f32x4_t poA[4] = {}, poB[4] = {};
    float mA = -1.9e8f, lA = 0.f, mB = -1.9e8f, lB = 0.f;

    __syncthreads();                  // prior segment's LDS readers done
    int buf = 0;
    STAGE_PH(ph0, 0);
    for (int ph = ph0; ph < ph1; ++ph) {
      __syncthreads();                // publishes phase ph; drains stage
      if (ph + 1 < ph1) STAGE_PH(ph + 1, buf ^ 1);
      const char* Ksb = smem + buf * 16384;
      const char* Vsb = smem + 32768 + buf * 16384;
      const int kb = ph * 128;

      f32x4_t mk0[4], mk1[4];
#pragma unroll
      for (int t = 0; t < 4; ++t) {
        mk0[t] = *reinterpret_cast<const f32x4_t*>(&mp[kb + t * 16 + lg * 4]);
        mk1[t] = *reinterpret_cast<const f32x4_t*>(&mp[kb + 64 + t * 16 + lg * 4]);
      }

      f32x4_t stA0[4], stB0[4], stA1[4], stB1[4];
      bf16x8_t pfA[2], pfB[2];
      if (ph < qst_) {
        __builtin_amdgcn_s_setprio(1);
        QK_SUB(0, stA0, stB0);
        QK_SUB(1, stA1, stB1);
        __builtin_amdgcn_s_setprio(0);
        SM_PACK(stA0, mk0, mA, lA, poA, pfA, qg0, false, 0);
        SM_PACK(stB0, mk0, mB, lB, poB, pfB, qg1, false, 0);
        __builtin_amdgcn_s_setprio(1);
        PV_SUB(0, pfA, pfB);
        __builtin_amdgcn_s_setprio(0);
        SM_PACK(stA1, mk1, mA, lA, poA, pfA, qg0, false, 0);
        SM_PACK(stB1, mk1, mB, lB, poB, pfB, qg1, false, 0);
        __builtin_amdgcn_s_setprio(1);
        PV_SUB(1, pfA, pfB);
        __builtin_amdgcn_s_setprio(0);
      } else {
        QK_SUB(0, stA0, stB0);
        SM_PACK(stA0, mk0, mA, lA, poA, pfA, qg0, true, kb);
        SM_PACK(stB0, mk0, mB, lB, poB, pfB, qg1, true, kb);
        PV_SUB(0, pfA, pfB);
        if (w >= 2) {
          QK_SUB(1, stA1, stB1);
          SM_PACK(stA1, mk1, mA, lA, poA, pfA, qg0, true, kb + 64);
          SM_PACK(stB1, mk1, mB, lB, poB, pfB, qg1, true, kb + 64);
          PV_SUB(1, pfA, pfB);
        }
      }
      buf ^= 1;
    }

    if (mode == 0) {
      float* Op = Opart + (size_t)slot * 8192;
      const int qa = w * 32 + l15, qb2 = qa + 16;
#pragma unroll
      for (int f = 0; f < 4; ++f) {
        *reinterpret_cast<f32x4_t*>(Op + qa  * 64 + f * 16 + lg * 4) = poA[f];
        *reinterpret_cast<f32x4_t*>(Op + qb2 * 64 + f * 16 + lg * 4) = poB[f];
      }
      if (lg == 0) {
        reinterpret_cast<float2*>(mlb)[slot * 128 + qa]  = make_float2(mA, lA);
        reinterpret_cast<float2*>(mlb)[slot * 128 + qb2] = make_float2(mB, lB);
      }
    } else {
      const float* vm = vmean + bh * DH;
      {
        const bool dead = (mA < -1.0e7f);
        const float inv = dead ? 0.f : 1.0f / lA;
        bf16_t* orow = ctxb + (size_t)(b * S_LEN + qg0) * DMODEL + h * DH;
#pragma unroll
        for (int f = 0; f < 4; ++f) {
          bf16x4_t o;
#pragma unroll
          for (int r = 0; r < 4; ++r) {
            int d = f * 16 + lg * 4 + r;
            o[r] = (bf16_t)(dead ? vm[d] : poA[f][r] * inv);
          }
          *reinterpret_cast<bf16x4_t*>(&orow[f * 16 + lg * 4]) = o;
        }
      }
      {
        const bool dead = (mB < -1.0e7f);
        const float inv = dead ? 0.f : 1.0f / lB;
        bf16_t* orow = ctxb + (size_t)(b * S_LEN + qg1) * DMODEL + h * DH;
#pragma unroll
        for (int f = 0; f < 4; ++f) {
          bf16x4_t o;
#pragma unroll
          for (int r = 0; r < 4; ++r) {
            int d = f * 16 + lg * 4 + r;
            o[r] = (bf16_t)(dead ? vm[d] : poB[f][r] * inv);
          }
          *reinterpret_cast<bf16x4_t*>(&orow[f * 16 + lg * 4]) = o;
        }
      }
    }
  };

  const int slotA = (bh * 8 + u) * 2;
  if (role == 0) {
    run_segment(sH, 0, 8, 0, slotA);                 // heavy head: 8 full phases
  } else {
    run_segment(sH, 8, sH + 1, 0, slotA + 1);        // heavy tail: 8-u phases
    run_segment(sL, 0, sL + 1, 1, 0);                // light stripe: u+1 phases
  }
#undef STAGE_PH
#undef QK_SUB
#undef SM_PACK
#undef PV_SUB
}

// ---------------- combine split-K partials for heavy stripes ----------------
__global__ __launch_bounds__(256)
void k_combine(const float* __restrict__ Op, const float* __restrict__ mlb,
               const float* __restrict__ vmean, bf16_t* __restrict__ ctxb) {
  const int u = blockIdx.x;                  // 0..7
  const int bh = blockIdx.y;                 // 0..31
  const int b = bh >> 4, h = bh & 15;
  const int qbase = (15 - u) * 128;
  const int t = threadIdx.x;
  const int q = t >> 1, half = (t & 1) * 32;
  const int slotA = (bh * 8 + u) * 2;
  const float2 A = reinterpret_cast<const float2*>(mlb)[slotA * 128 + q];
  const float2 B = reinterpret_cast<const float2*>(mlb)[(slotA + 1) * 128 + q];
  const float m = fmaxf(A.x, B.x);
  const bool dead = (m < -1.0e7f);
  const float wA = exp2f(A.x - m), wB = exp2f(B.x - m);
  const float inv = dead ? 0.f : 1.0f / (wA * A.y + wB * B.y);
  const float* OA = Op + (size_t)slotA * 8192 + q * 64 + half;
  const float* OB = OA + 8192;
  bf16_t* orow = ctxb + (size_t)(b * S_LEN + qbase + q) * DMODEL + h * DH + half;
  const float* vm = vmean + bh * DH + half;
#pragma unroll
  for (int i = 0; i < 8; ++i) {
    f32x4_t a = *reinterpret_cast<const f32x4_t*>(OA + 4 * i);
    f32x4_t c = *reinterpret_cast<const f32x4_t*>(OB + 4 * i);
    bf16x4_t o;
#pragma unroll
    for (int r = 0; r < 4; ++r)
      o[r] = (bf16_t)(dead ? vm[4 * i + r] : (wA * a[r] + wB * c[r]) * inv);
    *reinterpret_cast<bf16x4_t*>(orow + 4 * i) = o;
  }
}

extern "C" void kernel_launch(void* const* d_in, const int* in_sizes, int n_in,
                              void* d_out, int out_size, void* d_ws, size_t ws_size,
                              hipStream_t stream) {
  const float* x     = (const float*)d_in[0];
  const int*   amask = (const int*)d_in[1];
  const float* Wqkv  = (const float*)d_in[2];
  const float* bqkv  = (const float*)d_in[3];
  const float* Wproj = (const float*)d_in[4];
  const float* bproj = (const float*)d_in[5];
  float* out = (float*)d_out;

  char* ws = (char*)d_ws;
  // [0,16MB): xb + WqT + WpT during QKV phase; reused as split-K partials later.
  bf16_t* xb    = (bf16_t*)(ws);                      // 8 MB  [4096][1024]
  bf16_t* WqT   = (bf16_t*)(ws + (8llu  << 20));      // 6 MB  [3072][1024]
  bf16_t* WpT   = (bf16_t*)(ws + (14llu << 20));      // 2 MB  [1024][1024]
  float*  Opart = (float*) (ws);                      // 16 MB [512 slots][128][64] f32
  bf16_t* Qb    = (bf16_t*)(ws + (16llu << 20));      // 8 MB  [b,h,s,d]
  bf16_t* Kb    = (bf16_t*)(ws + (24llu << 20));      // 8 MB  [b,h,s,d]
  bf16_t* Vt    = (bf16_t*)(ws + (32llu << 20));      // 8 MB  [b,h,d,s]
  bf16_t* ctxb  = (bf16_t*)(ws + (40llu << 20));      // 8 MB  [4096][1024]
  float*  vmean = (float*) (ws + (48llu << 20));      // 8 KB  [32][64]
  float*  mskf  = (float*) (ws + (48llu << 20) + 65536);   // 16 KB [2][2048]
  float*  mlb   = (float*) (ws + (48llu << 20) + 131072);  // 512 KB [512][128]{m,l}

  k_cvt_bf16<<<4096, 256, 0, stream>>>(x, xb, (2 * S_LEN * DMODEL) / 4);
  k_mask<<<16, 256, 0, stream>>>(amask, mskf, 2 * S_LEN);
  k_transpose_bf16<<<dim3(3072 / 32, 1024 / 32), dim3(32, 8), 0, stream>>>(Wqkv, WqT, 1024, 3072);
  k_gemm<0><<<dim3(3072 / 128, 4096 / 128), 256, 0, stream>>>(
      xb, WqT, bqkv, Qb, Kb, Vt, nullptr, 4096, 3072, 1024);
  k_vmean<<<32, 256, 0, stream>>>(Vt, vmean);
  k_attn<<<dim3(32, 16), 256, 0, stream>>>(Qb, Kb, Vt, mskf, vmean, ctxb, Opart, mlb);
  k_combine<<<dim3(8, 32), 256, 0, stream>>>(Opart, mlb, vmean, ctxb);
  k_transpose_bf16<<<dim3(1024 / 32, 1024 / 32), dim3(32, 8), 0, stream>>>(Wproj, WpT, 1024, 1024);
  k_gemm<1><<<dim3(1024 / 64, 4096 / 128), 256, 0, stream>>>(
      ctxb, WpT, bproj, nullptr, nullptr, nullptr, out, 4096, 1024, 1024);
}

// Round 10
// 149.075 us; speedup vs baseline: 1.1724x; 1.1724x over previous
//
#include <hip/hip_runtime.h>
#include <hip/hip_bf16.h>
#include <stdint.h>

typedef __bf16 bf16_t;
typedef __bf16 bf16x4_t __attribute__((ext_vector_type(4)));
typedef __bf16 bf16x8_t __attribute__((ext_vector_type(8)));
typedef float f32x4_t __attribute__((ext_vector_type(4)));

#define S_LEN   2048
#define DMODEL  1024
#define NH      16
#define DH      64
// masks applied BEFORE scaling: masked logit = -1e9/8; work in log2 domain.
#define LOG2E   1.4426950408889634f
#define SCL     (0.125f * LOG2E)            // st * SCL == (st/8)*log2(e)
#define EPS2    (-1.8033688e8f)             // (-1e9/8) * log2(e)

#define MFMA(a, b, c) __builtin_amdgcn_mfma_f32_16x16x32_bf16(a, b, c, 0, 0, 0)

#define GLOAD_LDS16(gsrc, ldst)                                         \
  __builtin_amdgcn_global_load_lds(                                     \
      (__attribute__((address_space(1))) void*)(void*)(gsrc),           \
      (__attribute__((address_space(3))) void*)(void*)(ldst), 16, 0, 0)

// ---------------- fp32 -> bf16 convert (x) ----------------
__global__ void k_cvt_bf16(const float* __restrict__ in, bf16_t* __restrict__ out, int n4) {
  int i = blockIdx.x * blockDim.x + threadIdx.x;
  if (i >= n4) return;
  float4 v = reinterpret_cast<const float4*>(in)[i];
  bf16x4_t o = {(bf16_t)v.x, (bf16_t)v.y, (bf16_t)v.z, (bf16_t)v.w};
  reinterpret_cast<bf16x4_t*>(out)[i] = o;
}

// ---------------- pad mask -> additive log2-domain float ----------------
__global__ void k_mask(const int* __restrict__ am, float* __restrict__ mskf, int n) {
  int i = blockIdx.x * blockDim.x + threadIdx.x;
  if (i < n) mskf[i] = am[i] ? 0.f : EPS2;
}

// ---------------- fp32 [R][C] -> bf16 [C][R] (weight transpose) ----------------
__global__ void k_transpose_bf16(const float* __restrict__ in, bf16_t* __restrict__ out,
                                 int R, int C) {
  __shared__ float tile[32][33];
  int c0 = blockIdx.x * 32, r0 = blockIdx.y * 32;
  int tx = threadIdx.x, ty = threadIdx.y;   // block (32,8)
  for (int i = ty; i < 32; i += 8)
    tile[i][tx] = in[(size_t)(r0 + i) * C + (c0 + tx)];
  __syncthreads();
  for (int i = ty; i < 32; i += 8)
    out[(size_t)(c0 + i) * R + (r0 + tx)] = (bf16_t)tile[tx][i];
}

// ---------------- bf16 GEMM: C[M][N] = A[M][K] * Bt[N][K]^T + bias ----------------
// R7's verified inner loop (BK=64, counted vmcnt raw barriers, both-sides XOR
// swizzle = 0 bank conflicts) with single-round geometry:
// MODE 0: 128x192 tile -> grid 512 = exactly 2 blocks/CU (80 KB LDS), 1 round.
// MODE 1: 128x64  tile -> grid 512 = 2 blocks/CU, 1 round.
template<int MODE>
__global__ __launch_bounds__(256, 2)
void k_gemm(const bf16_t* __restrict__ A, const bf16_t* __restrict__ Bt,
            const float* __restrict__ bias,
            bf16_t* __restrict__ Qb, bf16_t* __restrict__ Kb, bf16_t* __restrict__ Vt,
            float* __restrict__ Out, int M, int N, int K) {
  constexpr int BN  = (MODE == 0) ? 192 : 64;   // block N-tile
  constexpr int JN  = BN / 32;                  // acc cols per wave (6 or 2)
  constexpr int BST = BN / 32;                  // B stage instrs per wave (6 or 2)
  __shared__ alignas(16) bf16_t As[2][128 * 64];
  __shared__ alignas(16) bf16_t Bs[2][BN * 64];
  const int tid = threadIdx.x;
  const int lane = tid & 63;
  const int w = tid >> 6;
  // T1: XCD-aware bijective swizzle (nwg = 512, % 8 == 0 for both call sites)
  const int nwg = gridDim.x * gridDim.y;
  int lin = blockIdx.y * gridDim.x + blockIdx.x;
  lin = (lin & 7) * (nwg >> 3) + (lin >> 3);
  const int m0 = (lin / gridDim.x) * 128;
  const int n0 = (lin % gridDim.x) * BN;
  const int wm = (w >> 1) * 64, wn = (w & 1) * (BN / 2);
  const int l15 = lane & 15, lg = lane >> 4;
  const int lrow = lane >> 3;                        // 0..7
  const int lcsw = (((lane & 7) ^ lrow) * 8);        // pre-swizzled source col (elems)
  const int swz8 = (l15 & 7) * 8;                    // read-side XOR (elems)

  f32x4_t acc[4][JN] = {};

#define GSTAGE(k0_, buf_)                                                        \
  do {                                                                           \
    _Pragma("unroll")                                                            \
    for (int p = 0; p < 4; ++p) {                                                \
      const int rb = w * 32 + p * 8;     /* wave-uniform 8-row group */          \
      GLOAD_LDS16(&A[(size_t)(m0 + rb + lrow) * K + (k0_) + lcsw],               \
                  &As[buf_][rb * 64]);                                           \
    }                                                                            \
    _Pragma("unroll")                                                            \
    for (int p = 0; p < BST; ++p) {                                              \
      const int rb = w * (BST * 8) + p * 8;                                      \
      GLOAD_LDS16(&Bt[(size_t)(n0 + rb + lrow) * K + (k0_) + lcsw],              \
                  &Bs[buf_][rb * 64]);                                           \
    }                                                                            \
  } while (0)

  GSTAGE(0, 0);
  int buf = 0;
  for (int k0 = 0; k0 < K; k0 += 64) {
    if (k0 + 64 < K) {
      GSTAGE(k0 + 64, buf ^ 1);          // prefetch stays in flight over barrier
      if (MODE == 0) asm volatile("s_waitcnt vmcnt(10)" ::: "memory");
      else           asm volatile("s_waitcnt vmcnt(6)"  ::: "memory");
    } else {
      asm volatile("s_waitcnt vmcnt(0)" ::: "memory");
    }
    __builtin_amdgcn_s_barrier();        // all waves' cur-tile loads landed
    __builtin_amdgcn_sched_barrier(0);
    const bf16_t* Asb = As[buf];
    const bf16_t* Bsb = Bs[buf];
#pragma unroll
    for (int kk = 0; kk < 64; kk += 32) {
      bf16x8_t a[4], b[JN];
      const int kof = kk + 8 * lg;
#pragma unroll
      for (int i = 0; i < 4; ++i)
        a[i] = *reinterpret_cast<const bf16x8_t*>(
            &Asb[(wm + i * 16 + l15) * 64 + (kof ^ swz8)]);
#pragma unroll
      for (int j = 0; j < JN; ++j)
        b[j] = *reinterpret_cast<const bf16x8_t*>(
            &Bsb[(wn + j * 16 + l15) * 64 + (kof ^ swz8)]);
      __builtin_amdgcn_s_setprio(1);
#pragma unroll
      for (int i = 0; i < 4; ++i)
#pragma unroll
        for (int j = 0; j < JN; ++j)
          acc[i][j] = MFMA(a[i], b[j], acc[i][j]);
      __builtin_amdgcn_s_setprio(0);
    }
    __builtin_amdgcn_sched_barrier(0);   // pin reads/MFMAs before the barrier
    __builtin_amdgcn_s_barrier();        // all waves done reading buf
    buf ^= 1;
  }
#undef GSTAGE

  const int rbase = lg * 4;
#pragma unroll
  for (int i = 0; i < 4; ++i)
#pragma unroll
    for (int j = 0; j < JN; ++j) {
      int ncol = n0 + wn + j * 16 + l15;
      float bs = bias[ncol];
#pragma unroll
      for (int r = 0; r < 4; ++r) {
        int m = m0 + wm + i * 16 + rbase + r;
        float v = acc[i][j][r] + bs;
        if (MODE == 1) {
          Out[(size_t)m * N + ncol] = v;
        } else {
          int b2 = m >> 11, s = m & 2047;         // S = 2048
          int t = ncol >> 10, nn = ncol & 1023;   // 0:Q 1:K 2:V
          int h = nn >> 6, d = nn & 63;
          size_t bh = (size_t)b2 * NH + h;
          if (t == 0)      Qb[(bh * S_LEN + s) * DH + d] = (bf16_t)v;
          else if (t == 1) Kb[(bh * S_LEN + s) * DH + d] = (bf16_t)v;
          else             Vt[(bh * DH + d) * S_LEN + s] = (bf16_t)v;
        }
      }
    }
}

// ---------------- per-(b,h) mean of V over all S keys (all-masked-row fallback) ------
__global__ __launch_bounds__(256)
void k_vmean(const bf16_t* __restrict__ Vt, float* __restrict__ vmean) {
  const int bh = blockIdx.x;
  const int t = threadIdx.x;
  const int d = t >> 2, q = t & 3;
  const bf16_t* vp = Vt + ((size_t)bh * DH + d) * S_LEN + q * 512;
  float s = 0.f;
  for (int i = 0; i < 512; i += 8) {
    bf16x8_t v = *reinterpret_cast<const bf16x8_t*>(&vp[i]);
    for (int j = 0; j < 8; ++j) s += (float)v[j];
  }
  __shared__ float part[256];
  part[t] = s;
  __syncthreads();
  if (q == 0)
    vmean[bh * DH + d] = (part[t] + part[t + 1] + part[t + 2] + part[t + 3]) * (1.f / 2048.f);
}

// ---------------- flash attention: 128-key phases, interleaved subtiles -------------
// (R7's verified version: block = 4 waves x 32 q-rows, pair-balanced stripes,
//  LDS K/V double-buffered with XOR-16 pre-swizzle, swapped-operand softmax,
//  cvt_pk P-pack, defer-max, peeled diagonal phase.)
__global__ __launch_bounds__(256, 2)
void k_attn(const bf16_t* __restrict__ Qb, const bf16_t* __restrict__ Kb,
            const bf16_t* __restrict__ Vt, const float* __restrict__ mskf,
            const float* __restrict__ vmean, bf16_t* __restrict__ ctxb) {
  __shared__ alignas(16) char smem[65536];   // K: 2 x 16KB @0; V^T: 2 x 16KB @32768
  const int tid = threadIdx.x, lane = tid & 63, w = tid >> 6;
  const int bh = blockIdx.x, b = bh >> 4, h = bh & 15;  // bh fast => K/V L2-resident
  const int y = blockIdx.y;
  const int qst = (y < 8) ? (15 - 2 * y) : (2 * (y - 8));  // pair-balanced stripes
  const int qbase = qst * 128 + w * 32;
  const int l15 = lane & 15, lg = lane >> 4;
  const int qg0 = qbase + l15, qg1 = qbase + 16 + l15;
  const bf16_t* Qp = Qb + (size_t)bh * S_LEN * DH;
  const char*   Kg = (const char*)(Kb + (size_t)bh * S_LEN * DH);  // row = key, 128 B
  const char*   Vg = (const char*)(Vt + (size_t)bh * DH * S_LEN);  // row = d, 4096 B
  const float*  mp = mskf + b * S_LEN;

  // staging lane constants (pre-swizzled global source cols, 16B units)
  const int srow = lane >> 3;                               // K: 8 rows/iter
  const int scol = ((lane & 7) * 16) ^ (srow * 16);
  const int vrow = lane >> 4;                               // V: 4 rows/iter
  const int swz  = 16 * (l15 & 7);

  const bf16x8_t qA0 = *reinterpret_cast<const bf16x8_t*>(&Qp[qg0 * DH + 8 * lg]);
  const bf16x8_t qA1 = *reinterpret_cast<const bf16x8_t*>(&Qp[qg0 * DH + 32 + 8 * lg]);
  const bf16x8_t qB0 = *reinterpret_cast<const bf16x8_t*>(&Qp[qg1 * DH + 8 * lg]);
  const bf16x8_t qB1 = *reinterpret_cast<const bf16x8_t*>(&Qp[qg1 * DH + 32 + 8 * lg]);

  f32x4_t poA[4] = {}, poB[4] = {};
  float mA = -1.9e8f, lA = 0.f;
  float mB = -1.9e8f, lB = 0.f;

#define STAGE_PH(ph_, buf_)                                                        \
  do {                                                                             \
    const int kb_ = (ph_) * 128;                                                   \
    _Pragma("unroll")                                                              \
    for (int jj = 0; jj < 4; ++jj) {                                               \
      const int rk = w * 32 + jj * 8;                                              \
      GLOAD_LDS16(Kg + (size_t)(kb_ + rk + srow) * 128 + scol,                     \
                  smem + (buf_) * 16384 + rk * 128);                               \
      const int rv = w * 16 + jj * 4;                                              \
      const int vc = ((lane & 15) * 16) ^ ((((jj << 2) + vrow) & 7) * 16);         \
      GLOAD_LDS16(Vg + (size_t)(rv + vrow) * 4096 + (size_t)kb_ * 2 + vc,          \
                  smem + 32768 + (buf_) * 16384 + rv * 256);                       \
    }                                                                              \
  } while (0)

#define QK_SUB(S_, STA, STB)                                                       \
  _Pragma("unroll")                                                                \
  for (int t = 0; t < 4; ++t) {                                                    \
    const int rbyte = ((S_) * 64 + t * 16 + l15) * 128;                            \
    bf16x8_t k0 = *reinterpret_cast<const bf16x8_t*>(Ksb + rbyte + ((16 * lg) ^ swz));       \
    bf16x8_t k1 = *reinterpret_cast<const bf16x8_t*>(Ksb + rbyte + ((64 + 16 * lg) ^ swz));  \
    f32x4_t s = {}; s = MFMA(k0, qA0, s); s = MFMA(k1, qA1, s); STA[t] = s;        \
    f32x4_t s2 = {}; s2 = MFMA(k0, qB0, s2); s2 = MFMA(k1, qB1, s2); STB[t] = s2;  \
  }

#define SM_PACK(ST, MK, M_, L_, PO, PF, QG, CAUSAL, KB0)                           \
  do {                                                                             \
    float e[16]; float pmax = -3.0e38f;                                            \
    _Pragma("unroll")                                                              \
    for (int t = 0; t < 4; ++t)                                                    \
      _Pragma("unroll")                                                            \
      for (int r = 0; r < 4; ++r) {                                                \
        float v = fmaf(ST[t][r], SCL, MK[t][r]);                                   \
        if (CAUSAL) {                                                              \
          int k = (KB0) + t * 16 + lg * 4 + r;                                     \
          v = (k <= (QG)) ? v : EPS2;                                              \
        }                                                                          \
        e[t * 4 + r] = v; pmax = fmaxf(pmax, v);                                   \
      }                                                                            \
    pmax = fmaxf(pmax, __shfl_xor(pmax, 16));                                      \
    pmax = fmaxf(pmax, __shfl_xor(pmax, 32));                                      \
    if (!__all(pmax <= (M_) + 8.f)) {                                              \
      float mn = fmaxf(M_, pmax); float sc = exp2f((M_) - mn);                     \
      M_ = mn; L_ *= sc;                                                           \
      _Pragma("unroll") for (int f = 0; f < 4; ++f) PO[f] *= sc;                   \
    }                                                                              \
    float ps = 0.f;                                                                \
    _Pragma("unroll")                                                              \
    for (int i = 0; i < 16; ++i) { e[i] = exp2f(e[i] - (M_)); ps += e[i]; }        \
    ps += __shfl_xor(ps, 16); ps += __shfl_xor(ps, 32);                            \
    L_ += ps;                                                                      \
    _Pragma("unroll")                                                              \
    for (int g = 0; g < 2; ++g) {                                                  \
      union { uint32_t u2[4]; bf16x8_t v; } pk_;                                   \
      _Pragma("unroll")                                                            \
      for (int jj = 0; jj < 4; ++jj)                                               \
        asm("v_cvt_pk_bf16_f32 %0, %1, %2"                                         \
            : "=v"(pk_.u2[jj]) : "v"(e[8 * g + 2 * jj]), "v"(e[8 * g + 2 * jj + 1])); \
      PF[g] = pk_.v;                                                               \
    }                                                                              \
  } while (0)

#define PV_SUB(S_, PFA, PFB)                                                       \
  _Pragma("unroll")                                                                \
  for (int g = 0; g < 2; ++g)                                                      \
    _Pragma("unroll")                                                              \
    for (int f = 0; f < 4; ++f) {                                                  \
      const int rbyte = (f * 16 + l15) * 256;                                      \
      const int cb = (S_) * 128 + 64 * g + 8 * lg;                                 \
      bf16x4_t va = *reinterpret_cast<const bf16x4_t*>(Vsb + rbyte + (cb ^ swz));          \
      bf16x4_t vb = *reinterpret_cast<const bf16x4_t*>(Vsb + rbyte + ((cb + 32) ^ swz));   \
      bf16x8_t vv = {va[0], va[1], va[2], va[3], vb[0], vb[1], vb[2], vb[3]};      \
      poA[f] = MFMA(vv, PFA[g], poA[f]);                                           \
      poB[f] = MFMA(vv, PFB[g], poB[f]);                                           \
    }

  int buf = 0;
  STAGE_PH(0, 0);

  // ---- full phases: no causal ops at all ----
  for (int ph = 0; ph < qst; ++ph) {
    const int kb = ph * 128;
    __syncthreads();                         // publishes phase ph; frees buf^1
    STAGE_PH(ph + 1, buf ^ 1);               // async; drains at next barrier
    const char* Ksb = smem + buf * 16384;
    const char* Vsb = smem + 32768 + buf * 16384;

    f32x4_t mk0[4], mk1[4];
#pragma unroll
    for (int t = 0; t < 4; ++t) {
      mk0[t] = *reinterpret_cast<const f32x4_t*>(&mp[kb + t * 16 + lg * 4]);
      mk1[t] = *reinterpret_cast<const f32x4_t*>(&mp[kb + 64 + t * 16 + lg * 4]);
    }

    f32x4_t stA0[4], stB0[4], stA1[4], stB1[4];
    __builtin_amdgcn_s_setprio(1);
    QK_SUB(0, stA0, stB0);
    QK_SUB(1, stA1, stB1);
    __builtin_amdgcn_s_setprio(0);

    bf16x8_t pfA[2], pfB[2];
    SM_PACK(stA0, mk0, mA, lA, poA, pfA, qg0, false, 0);
    SM_PACK(stB0, mk0, mB, lB, poB, pfB, qg1, false, 0);
    __builtin_amdgcn_s_setprio(1);
    PV_SUB(0, pfA, pfB);
    __builtin_amdgcn_s_setprio(0);
    SM_PACK(stA1, mk1, mA, lA, poA, pfA, qg0, false, 0);
    SM_PACK(stB1, mk1, mB, lB, poB, pfB, qg1, false, 0);
    __builtin_amdgcn_s_setprio(1);
    PV_SUB(1, pfA, pfB);
    __builtin_amdgcn_s_setprio(0);
    buf ^= 1;
  }

  // ---- diagonal phase (ph == qst): causal; sub1 only for waves 2,3 ----
  {
    const int kb = qst * 128;
    __syncthreads();
    const char* Ksb = smem + buf * 16384;
    const char* Vsb = smem + 32768 + buf * 16384;

    f32x4_t mk0[4], mk1[4];
#pragma unroll
    for (int t = 0; t < 4; ++t) {
      mk0[t] = *reinterpret_cast<const f32x4_t*>(&mp[kb + t * 16 + lg * 4]);
      mk1[t] = *reinterpret_cast<const f32x4_t*>(&mp[kb + 64 + t * 16 + lg * 4]);
    }

    f32x4_t stA0[4], stB0[4], stA1[4], stB1[4];
    bf16x8_t pfA[2], pfB[2];
    QK_SUB(0, stA0, stB0);
    SM_PACK(stA0, mk0, mA, lA, poA, pfA, qg0, true, kb);
    SM_PACK(stB0, mk0, mB, lB, poB, pfB, qg1, true, kb);
    PV_SUB(0, pfA, pfB);
    if (w >= 2) {                          // wave-uniform: sub1 exists only for w>=2
      QK_SUB(1, stA1, stB1);
      SM_PACK(stA1, mk1, mA, lA, poA, pfA, qg0, true, kb + 64);
      SM_PACK(stB1, mk1, mB, lB, poB, pfB, qg1, true, kb + 64);
      PV_SUB(1, pfA, pfB);
    }
  }
#undef STAGE_PH
#undef QK_SUB
#undef SM_PACK
#undef PV_SUB

  // ---- epilogue: normalize; all-masked rows -> uniform mean of V ----
  const float* vm = vmean + bh * DH;
  {
    const bool dead = (mA < -1.0e7f);
    const float inv = dead ? 0.f : 1.0f / lA;
    bf16_t* orow = ctxb + (size_t)(b * S_LEN + qg0) * DMODEL + h * DH;
#pragma unroll
    for (int f = 0; f < 4; ++f) {
      bf16x4_t o;
#pragma unroll
      for (int r = 0; r < 4; ++r) {
        int d = f * 16 + lg * 4 + r;
        o[r] = (bf16_t)(dead ? vm[d] : poA[f][r] * inv);
      }
      *reinterpret_cast<bf16x4_t*>(&orow[f * 16 + lg * 4]) = o;
    }
  }
  {
    const bool dead = (mB < -1.0e7f);
    const float inv = dead ? 0.f : 1.0f / lB;
    bf16_t* orow = ctxb + (size_t)(b * S_LEN + qg1) * DMODEL + h * DH;
#pragma unroll
    for (int f = 0; f < 4; ++f) {
      bf16x4_t o;
#pragma unroll
      for (int r = 0; r < 4; ++r) {
        int d = f * 16 + lg * 4 + r;
        o[r] = (bf16_t)(dead ? vm[d] : poB[f][r] * inv);
      }
      *reinterpret_cast<bf16x4_t*>(&orow[f * 16 + lg * 4]) = o;
    }
  }
}

extern "C" void kernel_launch(void* const* d_in, const int* in_sizes, int n_in,
                              void* d_out, int out_size, void* d_ws, size_t ws_size,
                              hipStream_t stream) {
  const float* x     = (const float*)d_in[0];
  const int*   amask = (const int*)d_in[1];
  const float* Wqkv  = (const float*)d_in[2];
  const float* bqkv  = (const float*)d_in[3];
  const float* Wproj = (const float*)d_in[4];
  const float* bproj = (const float*)d_in[5];
  float* out = (float*)d_out;

  char* ws = (char*)d_ws;
  bf16_t* xb    = (bf16_t*)(ws);                      // 8 MB  [4096][1024]
  bf16_t* WqT   = (bf16_t*)(ws + (8llu  << 20));      // 6 MB  [3072][1024]
  bf16_t* WpT   = (bf16_t*)(ws + (14llu << 20));      // 2 MB  [1024][1024]
  bf16_t* Qb    = (bf16_t*)(ws + (16llu << 20));      // 8 MB  [b,h,s,d]
  bf16_t* Kb    = (bf16_t*)(ws + (24llu << 20));      // 8 MB  [b,h,s,d]
  bf16_t* Vt    = (bf16_t*)(ws + (32llu << 20));      // 8 MB  [b,h,d,s]
  bf16_t* ctxb  = (bf16_t*)(ws + (40llu << 20));      // 8 MB  [4096][1024]
  float*  vmean = (float*) (ws + (48llu << 20));      // 8 KB  [32][64]
  float*  mskf  = (float*) (ws + (48llu << 20) + 65536);  // 16 KB [2][2048]

  k_cvt_bf16<<<4096, 256, 0, stream>>>(x, xb, (2 * S_LEN * DMODEL) / 4);
  k_mask<<<16, 256, 0, stream>>>(amask, mskf, 2 * S_LEN);
  k_transpose_bf16<<<dim3(3072 / 32, 1024 / 32), dim3(32, 8), 0, stream>>>(Wqkv, WqT, 1024, 3072);
  k_transpose_bf16<<<dim3(1024 / 32, 1024 / 32), dim3(32, 8), 0, stream>>>(Wproj, WpT, 1024, 1024);
  k_gemm<0><<<dim3(3072 / 192, 4096 / 128), 256, 0, stream>>>(
      xb, WqT, bqkv, Qb, Kb, Vt, nullptr, 4096, 3072, 1024);
  k_vmean<<<32, 256, 0, stream>>>(Vt, vmean);
  k_attn<<<dim3(32, 16), 256, 0, stream>>>(Qb, Kb, Vt, mskf, vmean, ctxb);
  k_gemm<1><<<dim3(1024 / 64, 4096 / 128), 256, 0, stream>>>(
      ctxb, WpT, bproj, nullptr, nullptr, nullptr, out, 4096, 1024, 1024);
}